// Round 9
// baseline (751.467 us; speedup 1.0000x reference)
//
#include <hip/hip_runtime.h>
#include <hip/hip_bf16.h>

#define NFFT   4194304
#define NMODES 2
#define NTAPS  101
#define NVALID (NFFT - NTAPS + 1)   // 4194204
#define N0     (NTAPS / 2)          // 50

constexpr int BLOCK = 256;
constexpr int CPT   = 8;                    // consecutive outputs per thread
constexpr int TILE  = BLOCK * CPT;          // 2048 outputs per block
constexpr int WIN   = TILE + NTAPS - 1;     // 2148 staged P samples
constexpr int PITCH = 269;                  // rows per phase (max row read = 268)

static __device__ __forceinline__ unsigned short f2bf(float x) {
    __hip_bfloat16 h = __float2bfloat16(x);
    return *reinterpret_cast<unsigned short*>(&h);
}
static __device__ __forceinline__ unsigned pk(float e0, float e1) {
    return (unsigned)f2bf(e0) | ((unsigned)f2bf(e1) << 16);
}

__global__ __launch_bounds__(BLOCK, 4) void nl_kernel(
    const float* __restrict__ xa,   // d_in[0] big stream (A)
    const float* __restrict__ xb,   // d_in[1] big stream (B)
    const float* __restrict__ W,  const float* __restrict__ b,
    const float* __restrict__ power, unsigned* __restrict__ out)
{
    // P element e lives at Pl[(e&7)*PITCH + (e>>3)] (phase-swizzled)
    __shared__ float2 Pl[CPT * PITCH];

    const int tid = threadIdx.x;
    const int tile_start = blockIdx.x * TILE;

    // ---- stage P = A^2 + B^2 into swizzled LDS ----
    const float2* __restrict__ xa2 = reinterpret_cast<const float2*>(xa);
    const float2* __restrict__ xb2 = reinterpret_cast<const float2*>(xb);
    for (int idx = tid; idx < WIN; idx += BLOCK) {
        const int g = tile_start + idx;
        float2 p = make_float2(0.f, 0.f);
        if (g < NFFT) {
            const float2 a = xa2[g];
            const float2 c = xb2[g];
            p.x = a.x * a.x + c.x * c.x;
            p.y = a.y * a.y + c.y * c.y;
        }
        Pl[(idx & 7) * PITCH + (idx >> 3)] = p;
    }
    __syncthreads();

    // ---- FIR, register-pipelined: blk0=[8k,8k+8), blk1=[8k+8,8k+16) cover
    // all taps of k-body; blk2=[8k+16,8k+24) prefetched a FULL k-body early.
    float acc[CPT][2];
    const float b0 = b[0], b1 = b[1];
    #pragma unroll
    for (int c = 0; c < CPT; ++c) { acc[c][0] = b0; acc[c][1] = b1; }

    const float4* __restrict__ W4 = reinterpret_cast<const float4*>(W);

    float2 blk0[8], blk1[8];
    #pragma unroll
    for (int m = 0; m < 8; ++m) blk0[m] = Pl[m * PITCH + tid];       // [0,8)+tid*8
    #pragma unroll
    for (int m = 0; m < 8; ++m) blk1[m] = Pl[m * PITCH + tid + 1];   // [8,16)+tid*8

    #pragma unroll
    for (int k = 0; k < 12; ++k) {                 // taps 0..95
        float2 blk2[8];
        #pragma unroll
        for (int m = 0; m < 8; ++m) blk2[m] = Pl[m * PITCH + tid + k + 2];
        #pragma unroll
        for (int j = 0; j < 8; ++j) {
            const float4 wt = W4[k * 8 + j];       // wave-uniform -> s_load
            #pragma unroll
            for (int c = 0; c < CPT; ++c) {
                const int e = j + c;               // compile-time
                const float2 p = (e < 8) ? blk0[e] : blk1[e - 8];
                acc[c][0] = fmaf(p.x, wt.x, fmaf(p.y, wt.z, acc[c][0]));
                acc[c][1] = fmaf(p.x, wt.y, fmaf(p.y, wt.w, acc[c][1]));
            }
        }
        #pragma unroll
        for (int m = 0; m < 8; ++m) { blk0[m] = blk1[m]; blk1[m] = blk2[m]; }
    }
    // tail taps 96..100: blk0=[96,104), blk1=[104,112)
    #pragma unroll
    for (int j = 0; j < 5; ++j) {
        const float4 wt = W4[96 + j];
        #pragma unroll
        for (int c = 0; c < CPT; ++c) {
            const int e = j + c;
            const float2 p = (e < 8) ? blk0[e] : blk1[e - 8];
            acc[c][0] = fmaf(p.x, wt.x, fmaf(p.y, wt.z, acc[c][0]));
            acc[c][1] = fmaf(p.x, wt.y, fmaf(p.y, wt.w, acc[c][1]));
        }
    }

    // ---- phase rotation + bf16 pack (verified R7 form) ----
    // elem0 = B*cos - A*sin ; elem1 = A*cos + B*sin, theta = acc*coef
    const float coef = 0.066268f * exp10f(power[0] * 0.1f);
    const int base = tile_start + tid * CPT;

    const float4* __restrict__ xa4 = reinterpret_cast<const float4*>(xa); // 2 samples
    const float4* __restrict__ xb4 = reinterpret_cast<const float4*>(xb);
    uint4* __restrict__ out4 = reinterpret_cast<uint4*>(out);             // 2 samples

    #pragma unroll
    for (int cc = 0; cc < 4; ++cc) {
        const int n0 = base + 2 * cc;              // even
        const int c0 = 2 * cc;
        if (n0 + 1 < NVALID) {                     // fast path: both samples valid
            const float4 A = xa4[(n0 + N0) >> 1];  // {s0.m0, s0.m1, s1.m0, s1.m1}
            const float4 B = xb4[(n0 + N0) >> 1];
            float s00, c00, s01, c01, s10, c10, s11, c11;
            __sincosf(acc[c0][0]     * coef, &s00, &c00);
            __sincosf(acc[c0][1]     * coef, &s01, &c01);
            __sincosf(acc[c0 + 1][0] * coef, &s10, &c10);
            __sincosf(acc[c0 + 1][1] * coef, &s11, &c11);
            uint4 o;
            o.x = pk(B.x * c00 - A.x * s00, A.x * c00 + B.x * s00); // s0 mode0
            o.y = pk(B.y * c01 - A.y * s01, A.y * c01 + B.y * s01); // s0 mode1
            o.z = pk(B.z * c10 - A.z * s10, A.z * c10 + B.z * s10); // s1 mode0
            o.w = pk(B.w * c11 - A.w * s11, A.w * c11 + B.w * s11); // s1 mode1
            out4[n0 >> 1] = o;
        } else {
            #pragma unroll
            for (int dc = 0; dc < 2; ++dc) {
                const int n = n0 + dc;
                if (n < NVALID) {
                    const float2 A = xa2[n + N0];
                    const float2 B = xb2[n + N0];
                    float s0, c0s, s1, c1s;
                    __sincosf(acc[c0 + dc][0] * coef, &s0, &c0s);
                    __sincosf(acc[c0 + dc][1] * coef, &s1, &c1s);
                    uint2 o;
                    o.x = pk(B.x * c0s - A.x * s0, A.x * c0s + B.x * s0);
                    o.y = pk(B.y * c1s - A.y * s1, A.y * c1s + B.y * s1);
                    reinterpret_cast<uint2*>(out)[n] = o;
                }
            }
        }
    }
}

extern "C" void kernel_launch(void* const* d_in, const int* in_sizes, int n_in,
                              void* d_out, int out_size, void* d_ws, size_t ws_size,
                              hipStream_t stream) {
    // Bind by size (robust): big arrays = x streams, 404 = W, 2 = b, 1 = power.
    const float* big[2] = {nullptr, nullptr};
    const float* W = nullptr; const float* b = nullptr; const float* power = nullptr;
    int nbig = 0;
    for (int i = 0; i < n_in; ++i) {
        const float* p = (const float*)d_in[i];
        const int sz = in_sizes[i];
        if (sz == NFFT * NMODES)       { if (nbig < 2) big[nbig++] = p; }
        else if (sz == NTAPS * NMODES * NMODES) { W = p; }
        else if (sz == NMODES)         { b = p; }
        else if (sz == 1)              { power = p; }
    }

    unsigned* out = (unsigned*)d_out;
    const int grid = (NVALID + TILE - 1) / TILE;  // 2048 blocks
    nl_kernel<<<grid, BLOCK, 0, stream>>>(big[0], big[1], W, b, power, out);
}

// Round 10
// 134.322 us; speedup vs baseline: 5.5945x; 5.5945x over previous
//
#include <hip/hip_runtime.h>
#include <hip/hip_bf16.h>

#define NFFT   4194304
#define NMODES 2
#define NTAPS  101
#define NVALID (NFFT - NTAPS + 1)   // 4194204
#define N0     (NTAPS / 2)          // 50

constexpr int BLOCK = 256;
constexpr int CPT   = 8;                    // consecutive outputs per thread
constexpr int TILE  = BLOCK * CPT;          // 2048 outputs per block
constexpr int WIN   = TILE + NTAPS - 1;     // 2148 staged P samples
constexpr int PITCH = 269;                  // rows per phase (max row touched = 268)

static __device__ __forceinline__ unsigned short f2bf(float x) {
    __hip_bfloat16 h = __float2bfloat16(x);
    return *reinterpret_cast<unsigned short*>(&h);
}
static __device__ __forceinline__ unsigned pk(float e0, float e1) {
    return (unsigned)f2bf(e0) | ((unsigned)f2bf(e1) << 16);
}

__global__ __launch_bounds__(BLOCK, 4) void nl_kernel(
    const float* __restrict__ xa,   // d_in[0] big stream (A)
    const float* __restrict__ xb,   // d_in[1] big stream (B)
    const float* __restrict__ W,  const float* __restrict__ b,
    const float* __restrict__ power, unsigned* __restrict__ out)
{
    // P element e (e = tid*8 + m) lives at Pl[(m&7)*PITCH + tid + (m>>3)]
    __shared__ float2 Pl[CPT * PITCH];

    const int tid = threadIdx.x;
    const int tile_start = blockIdx.x * TILE;

    // ---- stage P = A^2 + B^2 into phase-swizzled LDS ----
    const float2* __restrict__ xa2 = reinterpret_cast<const float2*>(xa);
    const float2* __restrict__ xb2 = reinterpret_cast<const float2*>(xb);
    for (int idx = tid; idx < WIN; idx += BLOCK) {
        const int g = tile_start + idx;
        float2 p = make_float2(0.f, 0.f);
        if (g < NFFT) {
            const float2 a = xa2[g];
            const float2 c = xb2[g];
            p.x = a.x * a.x + c.x * c.x;
            p.y = a.y * a.y + c.y * c.y;
        }
        Pl[(idx & 7) * PITCH + (idx >> 3)] = p;
    }
    __syncthreads();

    // ---- FIR with 16-slot register ring, NO rotation (slot m&15 == element m).
    // At tap t prefetch element t+15 into slot (t+15)&15 (== dead element t-1);
    // first consumed at tap t+8 -> ~8*68 cycles of LDS-latency cover.
    float acc[CPT][2];
    const float b0 = b[0], b1 = b[1];
    #pragma unroll
    for (int c = 0; c < CPT; ++c) { acc[c][0] = b0; acc[c][1] = b1; }

    const float4* __restrict__ W4 = reinterpret_cast<const float4*>(W);

    float2 w[16];
    #pragma unroll
    for (int m = 0; m < 15; ++m)              // prime elements 0..14
        w[m] = Pl[(m & 7) * PITCH + tid + (m >> 3)];

    for (int K = 0; K < 6; ++K) {             // taps 16K .. 16K+15  (0..95)
        const int krow = tid + 2 * K;
        #pragma unroll
        for (int j = 0; j < 16; ++j) {
            // prefetch element m = 16K + j + 15  -> slot (j+15)&15
            w[(j + 15) & 15] = Pl[((j + 7) & 7) * PITCH + krow + ((j + 15) >> 3)];
            const float4 wt = W4[16 * K + j];  // wave-uniform -> s_load
            #pragma unroll
            for (int c = 0; c < CPT; ++c) {
                const float2 p = w[(j + c) & 15];   // element 16K+j+c
                acc[c][0] = fmaf(p.x, wt.x, fmaf(p.y, wt.z, acc[c][0]));
                acc[c][1] = fmaf(p.x, wt.y, fmaf(p.y, wt.w, acc[c][1]));
            }
        }
    }
    // tail taps 96..100: elements 96..107 are in slots 0..11 (loaded in K=5)
    #pragma unroll
    for (int j = 0; j < 5; ++j) {
        const float4 wt = W4[96 + j];
        #pragma unroll
        for (int c = 0; c < CPT; ++c) {
            const float2 p = w[(96 + j + c) & 15];
            acc[c][0] = fmaf(p.x, wt.x, fmaf(p.y, wt.z, acc[c][0]));
            acc[c][1] = fmaf(p.x, wt.y, fmaf(p.y, wt.w, acc[c][1]));
        }
    }

    // ---- phase rotation + bf16 pack (verified R7 form) ----
    // elem0 = B*cos - A*sin ; elem1 = A*cos + B*sin, theta = acc*coef
    const float coef = 0.066268f * exp10f(power[0] * 0.1f);
    const int base = tile_start + tid * CPT;

    const float4* __restrict__ xa4 = reinterpret_cast<const float4*>(xa); // 2 samples
    const float4* __restrict__ xb4 = reinterpret_cast<const float4*>(xb);
    uint4* __restrict__ out4 = reinterpret_cast<uint4*>(out);             // 2 samples

    #pragma unroll
    for (int cc = 0; cc < 4; ++cc) {
        const int n0 = base + 2 * cc;              // even
        const int c0 = 2 * cc;
        if (n0 + 1 < NVALID) {                     // fast path: both samples valid
            const float4 A = xa4[(n0 + N0) >> 1];  // {s0.m0, s0.m1, s1.m0, s1.m1}
            const float4 B = xb4[(n0 + N0) >> 1];
            float s00, c00, s01, c01, s10, c10, s11, c11;
            __sincosf(acc[c0][0]     * coef, &s00, &c00);
            __sincosf(acc[c0][1]     * coef, &s01, &c01);
            __sincosf(acc[c0 + 1][0] * coef, &s10, &c10);
            __sincosf(acc[c0 + 1][1] * coef, &s11, &c11);
            uint4 o;
            o.x = pk(B.x * c00 - A.x * s00, A.x * c00 + B.x * s00); // s0 mode0
            o.y = pk(B.y * c01 - A.y * s01, A.y * c01 + B.y * s01); // s0 mode1
            o.z = pk(B.z * c10 - A.z * s10, A.z * c10 + B.z * s10); // s1 mode0
            o.w = pk(B.w * c11 - A.w * s11, A.w * c11 + B.w * s11); // s1 mode1
            out4[n0 >> 1] = o;
        } else {
            #pragma unroll
            for (int dc = 0; dc < 2; ++dc) {
                const int n = n0 + dc;
                if (n < NVALID) {
                    const float2 A = xa2[n + N0];
                    const float2 B = xb2[n + N0];
                    float s0, c0s, s1, c1s;
                    __sincosf(acc[c0 + dc][0] * coef, &s0, &c0s);
                    __sincosf(acc[c0 + dc][1] * coef, &s1, &c1s);
                    uint2 o;
                    o.x = pk(B.x * c0s - A.x * s0, A.x * c0s + B.x * s0);
                    o.y = pk(B.y * c1s - A.y * s1, A.y * c1s + B.y * s1);
                    reinterpret_cast<uint2*>(out)[n] = o;
                }
            }
        }
    }
}

extern "C" void kernel_launch(void* const* d_in, const int* in_sizes, int n_in,
                              void* d_out, int out_size, void* d_ws, size_t ws_size,
                              hipStream_t stream) {
    // Bind by size (robust): big arrays = x streams, 404 = W, 2 = b, 1 = power.
    const float* big[2] = {nullptr, nullptr};
    const float* W = nullptr; const float* b = nullptr; const float* power = nullptr;
    int nbig = 0;
    for (int i = 0; i < n_in; ++i) {
        const float* p = (const float*)d_in[i];
        const int sz = in_sizes[i];
        if (sz == NFFT * NMODES)       { if (nbig < 2) big[nbig++] = p; }
        else if (sz == NTAPS * NMODES * NMODES) { W = p; }
        else if (sz == NMODES)         { b = p; }
        else if (sz == 1)              { power = p; }
    }

    unsigned* out = (unsigned*)d_out;
    const int grid = (NVALID + TILE - 1) / TILE;  // 2048 blocks
    nl_kernel<<<grid, BLOCK, 0, stream>>>(big[0], big[1], W, b, power, out);
}